// Round 2
// baseline (139.805 us; speedup 1.0000x reference)
//
#include <hip/hip_runtime.h>
#include <hip/hip_bf16.h>
#include <stdint.h>
#include <stddef.h>

// Problem constants (from reference). fp32 in / fp32 out.
#define NUM_FEATURES 256
#define NUM_PIDS 5532
#define CQ_SIZE 5000
#define N_NONID 256
#define N_ROWS 2048
#define N_COLS (NUM_PIDS + CQ_SIZE + N_NONID)   // 10788
#define OIM_SCALAR 30.0f

// --- r6 design: bf16 fragment-permute pass + NO-LDS register GEMM ---
// r5 (137.5us, passed): convert + global_load_lds GEMM. Counters showed both
// our kernels < 54.6us each (hidden under harness fills); GEMM still carries
// 64KB LDS (2 blocks/CU), 4 barriers, LDS round-trip. But after the permute
// pass, every MFMA fragment sits at a lane-linear global address and the
// per-XCD working set (A 1MB + B-slab 0.66MB bf16) is L2-resident. So: load
// fragments global->VGPR directly (coalesced 16B/lane, L2-hit), ping-pong one
// k-slice ahead, ZERO LDS / ZERO barriers -> ~3 blocks/CU, no drain stalls.
// (Distinct from r4's failed no-LDS: that had uncoalesced fp32 gathers +
// nontemporal stores. This one is wave-coalesced bf16 + verified plain stores.)

#define BM 128
#define BN 128
#define KITERS 4                          // 4 k-tiles of 64 (8 k-slices of 32)

// XCD swizzle: 85 n-tiles padded to 88 = 8 XCDs * 11 tiles (r3-verified).
#define NT_PER_XCD 11
#define N_TILES 85
#define M_TILES 16
#define GRID_BLOCKS (8 * NT_PER_XCD * M_TILES)   // 1408 (48 dummy early-exit)

// Permuted layout: one chunk = 1 KiB = 64 lanes x 16 B = (16 rows x 32 k) bf16
// fragment slab: lane l <-> row rb*16+(l&15), k = ks*32 + (l>>4)*8 + j
// (exact mfma_16x16x32_bf16 A/B fragment layout). chunk(rb, ks) = rb*8 + ks.
#define B_ROWS_PAD (N_TILES * BN)        // 10880
#define A_RB (N_ROWS / 16)               // 128
#define B_RB (B_ROWS_PAD / 16)           // 680
#define A_CHUNKS (A_RB * 8)              // 1024
#define B_CHUNKS (B_RB * 8)              // 5440
#define WS_A_BYTES ((size_t)A_CHUNKS * 1024)   // 1 MiB
#define WS_B_BYTES ((size_t)B_CHUNKS * 1024)   // 5.3125 MiB
#define CONV_BLOCKS (((A_CHUNKS + B_CHUNKS) * 64) / 256)   // 1616

typedef __bf16 bf16_t;
typedef __bf16 bf16x4 __attribute__((ext_vector_type(4)));
typedef __bf16 bf16x8 __attribute__((ext_vector_type(8)));   // MFMA A/B frag
typedef float f32x4 __attribute__((ext_vector_type(4)));     // MFMA C/D frag

// ---------------- pass 1: fp32 -> bf16 fragment-permute (r5-verified) ----------------
__global__ __launch_bounds__(256)
void oim_convert_kernel(const float* __restrict__ A, const float* __restrict__ lut,
                        const float* __restrict__ cq, const float* __restrict__ nonid,
                        bf16_t* __restrict__ Aperm, bf16_t* __restrict__ Bperm) {
    const int tid  = blockIdx.x * 256 + threadIdx.x;
    const int lane = tid & 63;
    const int g    = tid >> 6;
    const int lr   = lane & 15;
    const int khi  = (lane >> 4) * 8;

    const float* src = nullptr;
    bf16_t* dst;
    if (g < A_CHUNKS) {
        const int ks = g & 7, rb = g >> 3;
        const int row = rb * 16 + lr;
        const int k0  = ks * 32 + khi;
        src = A + (size_t)row * NUM_FEATURES + k0;
        dst = Aperm + (size_t)g * 512 + lane * 8;
    } else {
        const int gb = g - A_CHUNKS;
        const int ks = gb & 7, rb = gb >> 3;
        const int row = rb * 16 + lr;
        const int k0  = ks * 32 + khi;
        dst = Bperm + (size_t)gb * 512 + lane * 8;
        if (row < NUM_PIDS)
            src = lut + (size_t)row * NUM_FEATURES + k0;
        else if (row < NUM_PIDS + CQ_SIZE)
            src = cq + (size_t)(row - NUM_PIDS) * NUM_FEATURES + k0;
        else if (row < N_COLS)
            src = nonid + (size_t)(row - NUM_PIDS - CQ_SIZE) * NUM_FEATURES + k0;
        // else: padded tail rows 10788..10879 -> zeros
    }
    bf16x8 v = {(bf16_t)0.f, (bf16_t)0.f, (bf16_t)0.f, (bf16_t)0.f,
                (bf16_t)0.f, (bf16_t)0.f, (bf16_t)0.f, (bf16_t)0.f};
    if (src) {
        const float4 a = *(const float4*)src;
        const float4 b = *(const float4*)(src + 4);
        v = bf16x8{(bf16_t)a.x, (bf16_t)a.y, (bf16_t)a.z, (bf16_t)a.w,
                   (bf16_t)b.x, (bf16_t)b.y, (bf16_t)b.z, (bf16_t)b.w};
    }
    *(bf16x8*)dst = v;
}

// ---------------- pass 2: no-LDS register-fragment GEMM ----------------
__global__ __launch_bounds__(256)
void oim_gemm_reg(const bf16_t* __restrict__ Aperm, const bf16_t* __restrict__ Bperm,
                  float* __restrict__ out) {
    const int id  = blockIdx.x;
    const int xcd = id & 7;
    const int l   = id >> 3;
    const int nt  = xcd * NT_PER_XCD + l % NT_PER_XCD;
    const int mt  = l / NT_PER_XCD;
    if (nt >= N_TILES) return;                 // dummy block (no barriers anywhere)
    const int m0 = mt * BM;
    const int n0 = nt * BN;

    const int tid  = threadIdx.x;
    const int wid  = tid >> 6;
    const int lane = tid & 63;

    const int rbA0 = (wid >> 1) * 4;           // wave's A row-block base (0 or 4)
    const int rbB0 = (wid & 1) * 4;            // wave's B row-block base (0 or 4)

    // frag (t, ks) lives at chunk (rb0+t)*8 + ks, byte addr chunk*1024 + lane*16
    const bf16_t* abase = Aperm + ((size_t)(mt * 8 + rbA0) * 8) * 512 + lane * 8;
    const bf16_t* bbase = Bperm + ((size_t)(nt * 8 + rbB0) * 8) * 512 + lane * 8;

    f32x4 acc[4][4] = {};
    bf16x8 af[2][4], bfr[2][4];                // ping-pong k-slices (static idx)

    // prologue: k-slice 0
    #pragma unroll
    for (int t = 0; t < 4; ++t) {
        af[0][t]  = *(const bf16x8*)(abase + (size_t)(t * 8 + 0) * 512);
        bfr[0][t] = *(const bf16x8*)(bbase + (size_t)(t * 8 + 0) * 512);
    }

    // 8 k-slices of K=32; prefetch slice ks+1 while MFMAing slice ks.
    #pragma unroll
    for (int ks = 0; ks < 8; ++ks) {
        const int cur = ks & 1, nxt = cur ^ 1;   // compile-time under full unroll
        if (ks < 7) {
            #pragma unroll
            for (int t = 0; t < 4; ++t) {
                af[nxt][t]  = *(const bf16x8*)(abase + (size_t)(t * 8 + ks + 1) * 512);
                bfr[nxt][t] = *(const bf16x8*)(bbase + (size_t)(t * 8 + ks + 1) * 512);
            }
        }
        #pragma unroll
        for (int tm = 0; tm < 4; ++tm)
            #pragma unroll
            for (int tn = 0; tn < 4; ++tn)
                acc[tm][tn] = __builtin_amdgcn_mfma_f32_16x16x32_bf16(
                    af[cur][tm], bfr[cur][tn], acc[tm][tn], 0, 0, 0);
    }

    // epilogue: scale by 30, plain fp32 stores (r2-verified exact WRITE_SIZE;
    // do NOT use nontemporal -- r4 amplified writes 90->150 MB)
    const int wave_m = (wid >> 1) * 64;
    const int wave_n = (wid & 1) * 64;
    #pragma unroll
    for (int tm = 0; tm < 4; ++tm) {
        const int row_base = m0 + wave_m + tm * 16 + (lane >> 4) * 4;
        #pragma unroll
        for (int tn = 0; tn < 4; ++tn) {
            const int col = n0 + wave_n + tn * 16 + (lane & 15);
            if (col < N_COLS) {
                #pragma unroll
                for (int i = 0; i < 4; ++i)
                    out[(size_t)(row_base + i) * N_COLS + col] =
                        acc[tm][tn][i] * OIM_SCALAR;
            }
        }
    }
}

// ---------------- fallback: r3-verified fused kernel (if ws too small) ----------------
__global__ __launch_bounds__(256)
void oim_gemm_kernel(const float* __restrict__ A, const float* __restrict__ lut,
                     const float* __restrict__ cq, const float* __restrict__ nonid,
                     float* __restrict__ out) {
    __shared__ __align__(16) bf16_t As[2][BM * 32];
    __shared__ __align__(16) bf16_t Bs[2][BM * 32];

    const int id  = blockIdx.x;
    const int xcd = id & 7;
    const int l   = id >> 3;
    const int nt  = xcd * NT_PER_XCD + l % NT_PER_XCD;
    const int mt  = l / NT_PER_XCD;
    if (nt >= N_TILES) return;
    const int m0 = mt * BM;
    const int n0 = nt * BN;

    const int tid  = threadIdx.x;
    const int wid  = tid >> 6;
    const int lane = tid & 63;

    const int srow = tid >> 3;
    const int skk  = (tid & 7) * 4;

    const float* arow[4];
    const float* brow[4];
    #pragma unroll
    for (int j = 0; j < 4; ++j) {
        const int rm = m0 + srow + j * 32;
        arow[j] = A + (size_t)rm * NUM_FEATURES + skk;
        int r = n0 + srow + j * 32;
        r = r < (N_COLS - 1) ? r : (N_COLS - 1);
        const float* src;
        if (r < NUM_PIDS)                 src = lut   + (size_t)r * NUM_FEATURES;
        else if (r < NUM_PIDS + CQ_SIZE)  src = cq    + (size_t)(r - NUM_PIDS) * NUM_FEATURES;
        else                              src = nonid + (size_t)(r - NUM_PIDS - CQ_SIZE) * NUM_FEATURES;
        brow[j] = src + skk;
    }

    const int wave_m = (wid >> 1) * 64;
    const int wave_n = (wid & 1) * 64;
    const int fr = lane & 15;
    const int fk = (lane >> 4) * 8;

    f32x4 acc[4][4] = {};

    float4 areg[4], breg[4];
    #pragma unroll
    for (int j = 0; j < 4; ++j) {
        areg[j] = *(const float4*)arow[j];
        breg[j] = *(const float4*)brow[j];
        arow[j] += 32;
        brow[j] += 32;
    }

    #pragma unroll
    for (int kt = 0; kt < 8; ++kt) {
        bf16_t* const as = As[kt & 1];
        bf16_t* const bs = Bs[kt & 1];
        #pragma unroll
        for (int j = 0; j < 4; ++j) {
            const int ldix = (srow + j * 32) * 32 + skk;
            bf16x4 ac = { (bf16_t)areg[j].x, (bf16_t)areg[j].y,
                          (bf16_t)areg[j].z, (bf16_t)areg[j].w };
            bf16x4 bc = { (bf16_t)breg[j].x, (bf16_t)breg[j].y,
                          (bf16_t)breg[j].z, (bf16_t)breg[j].w };
            *(bf16x4*)&as[ldix] = ac;
            *(bf16x4*)&bs[ldix] = bc;
        }
        if (kt < 7) {
            #pragma unroll
            for (int j = 0; j < 4; ++j) {
                areg[j] = *(const float4*)arow[j];
                breg[j] = *(const float4*)brow[j];
                arow[j] += 32;
                brow[j] += 32;
            }
        }
        __syncthreads();

        bf16x8 af[4], bfr[4];
        #pragma unroll
        for (int t = 0; t < 4; ++t) {
            af[t]  = *(const bf16x8*)&as[(wave_m + t * 16 + fr) * 32 + fk];
            bfr[t] = *(const bf16x8*)&bs[(wave_n + t * 16 + fr) * 32 + fk];
        }
        #pragma unroll
        for (int tm = 0; tm < 4; ++tm)
            #pragma unroll
            for (int tn = 0; tn < 4; ++tn)
                acc[tm][tn] = __builtin_amdgcn_mfma_f32_16x16x32_bf16(
                    af[tm], bfr[tn], acc[tm][tn], 0, 0, 0);
    }

    #pragma unroll
    for (int tm = 0; tm < 4; ++tm) {
        const int row_base = m0 + wave_m + tm * 16 + (lane >> 4) * 4;
        #pragma unroll
        for (int tn = 0; tn < 4; ++tn) {
            const int col = n0 + wave_n + tn * 16 + (lane & 15);
            if (col < N_COLS) {
                #pragma unroll
                for (int i = 0; i < 4; ++i)
                    out[(size_t)(row_base + i) * N_COLS + col] =
                        acc[tm][tn][i] * OIM_SCALAR;
            }
        }
    }
}

extern "C" void kernel_launch(void* const* d_in, const int* in_sizes, int n_in,
                              void* d_out, int out_size, void* d_ws, size_t ws_size,
                              hipStream_t stream) {
    // setup_inputs() order:
    // 0: inputs [2048,256], 1: non_id_feat [256,256], 2: lut [5532,256],
    // 3: cq [5000,256], 4: first_pos_sample, 5: second_pos_sample,
    // 6: targets (int), 7: belong_to_first_half, 8: header
    const float* inputs = (const float*)d_in[0];
    const float* nonid  = (const float*)d_in[1];
    const float* lut    = (const float*)d_in[2];
    const float* cq     = (const float*)d_in[3];
    float* out = (float*)d_out;

    const size_t ws_need = WS_A_BYTES + WS_B_BYTES;   // ~6.32 MiB
    if (d_ws != nullptr && ws_size >= ws_need) {
        bf16_t* Aperm = (bf16_t*)d_ws;
        bf16_t* Bperm = (bf16_t*)((char*)d_ws + WS_A_BYTES);
        oim_convert_kernel<<<dim3(CONV_BLOCKS), 256, 0, stream>>>(
            inputs, lut, cq, nonid, Aperm, Bperm);
        oim_gemm_reg<<<dim3(GRID_BLOCKS), 256, 0, stream>>>(Aperm, Bperm, out);
    } else {
        oim_gemm_kernel<<<dim3(GRID_BLOCKS), 256, 0, stream>>>(
            inputs, lut, cq, nonid, out);
    }
}

// Round 3
// 135.304 us; speedup vs baseline: 1.0333x; 1.0333x over previous
//
#include <hip/hip_runtime.h>
#include <hip/hip_bf16.h>
#include <stdint.h>
#include <stddef.h>

// Problem constants (from reference). fp32 in / fp32 out.
#define NUM_FEATURES 256
#define NUM_PIDS 5532
#define CQ_SIZE 5000
#define N_NONID 256
#define N_ROWS 2048
#define N_COLS (NUM_PIDS + CQ_SIZE + N_NONID)   // 10788
#define OIM_SCALAR 30.0f

// --- r7 design: r5 DMA GEMM (measured best, 137.5us) + LDS-transpose
// dwordx4 epilogue. Evidence: r5 (LDS/DMA) vs r6 (no-LDS reg) differ by only
// 2.3us -> main loop is not dominant. Per-iter timeline = 2 harness fills
// (~110us, writing exactly 4x out-buffer at 76-80% peak) + our ~27us. Floor
// for our part ~18-20us; the untested lever is store-path efficiency: plain
// dword stores cover 4 rows x 64B per wave-inst, vs fills' sequential
// dwordx4 at 6.4 TB/s. New epilogue transposes each wave's 16x64 fp32 slab
// through LDS (dead after K-loop; buffers[0] safe after kt=2 barrier) and
// stores 256B-contiguous float4 runs, 1KB/wave-inst.

#define BM 128
#define BN 128
#define BK 64
#define KITERS (NUM_FEATURES / BK)   // 4

// XCD swizzle: 85 n-tiles padded to 88 = 8 XCDs * 11 tiles (r3-verified).
#define NT_PER_XCD 11
#define N_TILES 85
#define M_TILES 16
#define GRID_BLOCKS (8 * NT_PER_XCD * M_TILES)   // 1408 (48 dummy early-exit)

// Permuted layout: one chunk = 1 KiB = 64 lanes x 16 B = (16 rows x 32 k) bf16
// fragment slab: lane l <-> row rb*16+(l&15), k = ks*32 + (l>>4)*8 + j
// (exact mfma_16x16x32_bf16 A/B fragment layout). chunk(rb, ks) = rb*8 + ks.
#define B_ROWS_PAD (N_TILES * BN)        // 10880
#define A_RB (N_ROWS / 16)               // 128
#define B_RB (B_ROWS_PAD / 16)           // 680
#define A_CHUNKS (A_RB * 8)              // 1024
#define B_CHUNKS (B_RB * 8)              // 5440
#define WS_A_BYTES ((size_t)A_CHUNKS * 1024)   // 1 MiB
#define WS_B_BYTES ((size_t)B_CHUNKS * 1024)   // 5.3125 MiB
#define CONV_BLOCKS (((A_CHUNKS + B_CHUNKS) * 64) / 256)   // 1616

// Epilogue transpose buffer: per-wave 16 rows x 68 dwords (stride 68 = 64+4:
// ds_write banks (4r+c)%32 -> groups of 16 lanes hit 16 distinct banks, 2-way
// across half-waves = free per m136). 4352 B per wave.
#define EP_STRIDE 68

typedef __bf16 bf16_t;
typedef __bf16 bf16x4 __attribute__((ext_vector_type(4)));
typedef __bf16 bf16x8 __attribute__((ext_vector_type(8)));   // MFMA A/B frag
typedef float f32x4 __attribute__((ext_vector_type(4)));     // MFMA C/D frag

__device__ __forceinline__ void gload16(const void* g, void* l) {
    __builtin_amdgcn_global_load_lds(
        (const __attribute__((address_space(1))) void*)g,
        (__attribute__((address_space(3))) void*)l, 16, 0, 0);
}

// ---------------- pass 1: fp32 -> bf16 fragment-permute (r5/r6-verified) ----------------
__global__ __launch_bounds__(256)
void oim_convert_kernel(const float* __restrict__ A, const float* __restrict__ lut,
                        const float* __restrict__ cq, const float* __restrict__ nonid,
                        bf16_t* __restrict__ Aperm, bf16_t* __restrict__ Bperm) {
    const int tid  = blockIdx.x * 256 + threadIdx.x;
    const int lane = tid & 63;
    const int g    = tid >> 6;
    const int lr   = lane & 15;
    const int khi  = (lane >> 4) * 8;

    const float* src = nullptr;
    bf16_t* dst;
    if (g < A_CHUNKS) {
        const int ks = g & 7, rb = g >> 3;
        const int row = rb * 16 + lr;
        const int k0  = ks * 32 + khi;
        src = A + (size_t)row * NUM_FEATURES + k0;
        dst = Aperm + (size_t)g * 512 + lane * 8;
    } else {
        const int gb = g - A_CHUNKS;
        const int ks = gb & 7, rb = gb >> 3;
        const int row = rb * 16 + lr;
        const int k0  = ks * 32 + khi;
        dst = Bperm + (size_t)gb * 512 + lane * 8;
        if (row < NUM_PIDS)
            src = lut + (size_t)row * NUM_FEATURES + k0;
        else if (row < NUM_PIDS + CQ_SIZE)
            src = cq + (size_t)(row - NUM_PIDS) * NUM_FEATURES + k0;
        else if (row < N_COLS)
            src = nonid + (size_t)(row - NUM_PIDS - CQ_SIZE) * NUM_FEATURES + k0;
        // else: padded tail rows 10788..10879 -> zeros
    }
    bf16x8 v = {(bf16_t)0.f, (bf16_t)0.f, (bf16_t)0.f, (bf16_t)0.f,
                (bf16_t)0.f, (bf16_t)0.f, (bf16_t)0.f, (bf16_t)0.f};
    if (src) {
        const float4 a = *(const float4*)src;
        const float4 b = *(const float4*)(src + 4);
        v = bf16x8{(bf16_t)a.x, (bf16_t)a.y, (bf16_t)a.z, (bf16_t)a.w,
                   (bf16_t)b.x, (bf16_t)b.y, (bf16_t)b.z, (bf16_t)b.w};
    }
    *(bf16x8*)dst = v;
}

// ---------------- pass 2: DMA-staged bf16 GEMM + transposed epilogue ----------------
__global__ __launch_bounds__(256)
void oim_gemm_dma(const bf16_t* __restrict__ Aperm, const bf16_t* __restrict__ Bperm,
                  float* __restrict__ out) {
    __shared__ __align__(16) bf16_t As[2][BM * BK];   // 2 x 16 KiB
    __shared__ __align__(16) bf16_t Bs[2][BN * BK];   // 2 x 16 KiB  (64 KiB total)

    const int id  = blockIdx.x;
    const int xcd = id & 7;
    const int l   = id >> 3;
    const int nt  = xcd * NT_PER_XCD + l % NT_PER_XCD;
    const int mt  = l / NT_PER_XCD;
    if (nt >= N_TILES) return;                 // dummy block (uniform, pre-barrier)
    const int m0 = mt * BM;
    const int n0 = nt * BN;

    const int tid  = threadIdx.x;
    const int wid  = tid >> 6;
    const int lane = tid & 63;

    // DMA plan per wave: op j -> (rb_local = wid*2 + (j>>1), kc = j&1);
    // LDS chunk = wid*4 + j -> linear LDS dest, linear global source.
    const bf16_t* agp[4];
    const bf16_t* bgp[4];
    int ldsoff[4];
    #pragma unroll
    for (int j = 0; j < 4; ++j) {
        const int rbl = wid * 2 + (j >> 1);
        const int kc  = j & 1;
        agp[j] = Aperm + (size_t)(mt * 8 + rbl) * 4096 + kc * 512 + lane * 8;
        bgp[j] = Bperm + (size_t)(nt * 8 + rbl) * 4096 + kc * 512 + lane * 8;
        ldsoff[j] = (wid * 4 + j) * 512;       // bf16 units (1 KiB chunks)
    }

    const int rbA0 = (wid >> 1) * 4;           // wave's A row-block base
    const int rbB0 = (wid & 1) * 4;            // wave's B row-block base

    f32x4 acc[4][4] = {};

    // prologue: stage k-tile 0
    #pragma unroll
    for (int j = 0; j < 4; ++j) {
        gload16(agp[j], &As[0][ldsoff[j]]);
        gload16(bgp[j], &Bs[0][ldsoff[j]]);
    }
    __syncthreads();   // vmcnt(0) drain + barrier: tile 0 ready

    // verified 2-phase recipe: STAGE(next) -> compute(cur) -> syncthreads
    #pragma unroll
    for (int kt = 0; kt < KITERS; ++kt) {
        const bf16_t* const as = As[kt & 1];
        const bf16_t* const bs = Bs[kt & 1];
        if (kt < KITERS - 1) {
            bf16_t* const asn = As[(kt + 1) & 1];
            bf16_t* const bsn = Bs[(kt + 1) & 1];
            const int ko = (kt + 1) * 1024;    // +2048 B per k-tile, in bf16 units
            #pragma unroll
            for (int j = 0; j < 4; ++j) {
                gload16(agp[j] + ko, &asn[ldsoff[j]]);
                gload16(bgp[j] + ko, &bsn[ldsoff[j]]);
            }
        }
        // fragment loads: lane-linear 16B reads -> conflict-free
        bf16x8 af[2][4], bfr[2][4];
        #pragma unroll
        for (int kc = 0; kc < 2; ++kc) {
            #pragma unroll
            for (int t = 0; t < 4; ++t) {
                af[kc][t]  = *(const bf16x8*)&as[(((rbA0 + t) * 2 + kc) * 64 + lane) * 8];
                bfr[kc][t] = *(const bf16x8*)&bs[(((rbB0 + t) * 2 + kc) * 64 + lane) * 8];
            }
        }
        #pragma unroll
        for (int kc = 0; kc < 2; ++kc)
            #pragma unroll
            for (int tm = 0; tm < 4; ++tm)
                #pragma unroll
                for (int tn = 0; tn < 4; ++tn)
                    acc[tm][tn] = __builtin_amdgcn_mfma_f32_16x16x32_bf16(
                        af[kc][tm], bfr[kc][tn], acc[tm][tn], 0, 0, 0);
        if (kt < KITERS - 1) __syncthreads();  // drains next-tile DMA + WAR protect
    }

    // --- transposed epilogue ---
    // K-loop's last tile (kt=3) lives in buffers[1]; buffers[0] (As[0]/Bs[0],
    // 32 KiB) had their last reads at kt=2, sealed by kt=2's __syncthreads ->
    // safe to reuse per-wave with NO block barrier. Waves 0-2 stage in As[0]
    // (3 * 4352 B = 13056 <= 16384), wave 3 in Bs[0].
    float* const ep = (wid < 3) ? ((float*)&As[0][0] + wid * (16 * EP_STRIDE))
                                : ((float*)&Bs[0][0]);
    const int wave_m = (wid >> 1) * 64;
    const int wave_n = (wid & 1) * 64;
    const int hi  = lane >> 4;                 // 0..3
    const int lo  = lane & 15;                 // 0..15

    #pragma unroll
    for (int tm = 0; tm < 4; ++tm) {
        // stage: acc frag (row=(hi*4+i), col=tn*16+lo) -> ep[r*68 + c]
        #pragma unroll
        for (int tn = 0; tn < 4; ++tn)
            #pragma unroll
            for (int i = 0; i < 4; ++i)
                ep[(hi * 4 + i) * EP_STRIDE + tn * 16 + lo] =
                    acc[tm][tn][i] * OIM_SCALAR;
        // cross-lane LDS reuse within the wave: compiler can't see the dep
        // (rule #18) -- explicit drain + scheduling fence.
        asm volatile("s_waitcnt lgkmcnt(0)" ::: "memory");
        __builtin_amdgcn_sched_barrier(0);
        // read back transposed: lane -> (row = r4*4 + hi, 4 cols at lo*4),
        // store 16B float4, 256B contiguous per row, 1KB per wave-inst.
        #pragma unroll
        for (int r4 = 0; r4 < 4; ++r4) {
            const int lrow = r4 * 4 + hi;      // 0..15
            const f32x4 v = *(const f32x4*)&ep[lrow * EP_STRIDE + lo * 4];
            const int grow = m0 + wave_m + tm * 16 + lrow;
            const int gcol = n0 + wave_n + lo * 4;
            if (gcol < N_COLS) {               // both mult-of-4 -> whole-vec guard
                float4 sv = { v[0], v[1], v[2], v[3] };
                *(float4*)&out[(size_t)grow * N_COLS + gcol] = sv;
            }
        }
        // WAR to same ep region next tm: DS pipe is in-order per wave; pin the
        // compiler's ordering too.
        __builtin_amdgcn_sched_barrier(0);
    }
}

// ---------------- fallback: r3-verified fused kernel (if ws too small) ----------------
__global__ __launch_bounds__(256)
void oim_gemm_kernel(const float* __restrict__ A, const float* __restrict__ lut,
                     const float* __restrict__ cq, const float* __restrict__ nonid,
                     float* __restrict__ out) {
    __shared__ __align__(16) bf16_t As[2][BM * 32];
    __shared__ __align__(16) bf16_t Bs[2][BM * 32];

    const int id  = blockIdx.x;
    const int xcd = id & 7;
    const int l   = id >> 3;
    const int nt  = xcd * NT_PER_XCD + l % NT_PER_XCD;
    const int mt  = l / NT_PER_XCD;
    if (nt >= N_TILES) return;
    const int m0 = mt * BM;
    const int n0 = nt * BN;

    const int tid  = threadIdx.x;
    const int wid  = tid >> 6;
    const int lane = tid & 63;

    const int srow = tid >> 3;
    const int skk  = (tid & 7) * 4;

    const float* arow[4];
    const float* brow[4];
    #pragma unroll
    for (int j = 0; j < 4; ++j) {
        const int rm = m0 + srow + j * 32;
        arow[j] = A + (size_t)rm * NUM_FEATURES + skk;
        int r = n0 + srow + j * 32;
        r = r < (N_COLS - 1) ? r : (N_COLS - 1);
        const float* src;
        if (r < NUM_PIDS)                 src = lut   + (size_t)r * NUM_FEATURES;
        else if (r < NUM_PIDS + CQ_SIZE)  src = cq    + (size_t)(r - NUM_PIDS) * NUM_FEATURES;
        else                              src = nonid + (size_t)(r - NUM_PIDS - CQ_SIZE) * NUM_FEATURES;
        brow[j] = src + skk;
    }

    const int wave_m = (wid >> 1) * 64;
    const int wave_n = (wid & 1) * 64;
    const int fr = lane & 15;
    const int fk = (lane >> 4) * 8;

    f32x4 acc[4][4] = {};

    float4 areg[4], breg[4];
    #pragma unroll
    for (int j = 0; j < 4; ++j) {
        areg[j] = *(const float4*)arow[j];
        breg[j] = *(const float4*)brow[j];
        arow[j] += 32;
        brow[j] += 32;
    }

    #pragma unroll
    for (int kt = 0; kt < 8; ++kt) {
        bf16_t* const as = As[kt & 1];
        bf16_t* const bs = Bs[kt & 1];
        #pragma unroll
        for (int j = 0; j < 4; ++j) {
            const int ldix = (srow + j * 32) * 32 + skk;
            bf16x4 ac = { (bf16_t)areg[j].x, (bf16_t)areg[j].y,
                          (bf16_t)areg[j].z, (bf16_t)areg[j].w };
            bf16x4 bc = { (bf16_t)breg[j].x, (bf16_t)breg[j].y,
                          (bf16_t)breg[j].z, (bf16_t)breg[j].w };
            *(bf16x4*)&as[ldix] = ac;
            *(bf16x4*)&bs[ldix] = bc;
        }
        if (kt < 7) {
            #pragma unroll
            for (int j = 0; j < 4; ++j) {
                areg[j] = *(const float4*)arow[j];
                breg[j] = *(const float4*)brow[j];
                arow[j] += 32;
                brow[j] += 32;
            }
        }
        __syncthreads();

        bf16x8 af[4], bfr[4];
        #pragma unroll
        for (int t = 0; t < 4; ++t) {
            af[t]  = *(const bf16x8*)&as[(wave_m + t * 16 + fr) * 32 + fk];
            bfr[t] = *(const bf16x8*)&bs[(wave_n + t * 16 + fr) * 32 + fk];
        }
        #pragma unroll
        for (int tm = 0; tm < 4; ++tm)
            #pragma unroll
            for (int tn = 0; tn < 4; ++tn)
                acc[tm][tn] = __builtin_amdgcn_mfma_f32_16x16x32_bf16(
                    af[tm], bfr[tn], acc[tm][tn], 0, 0, 0);
    }

    #pragma unroll
    for (int tm = 0; tm < 4; ++tm) {
        const int row_base = m0 + wave_m + tm * 16 + (lane >> 4) * 4;
        #pragma unroll
        for (int tn = 0; tn < 4; ++tn) {
            const int col = n0 + wave_n + tn * 16 + (lane & 15);
            if (col < N_COLS) {
                #pragma unroll
                for (int i = 0; i < 4; ++i)
                    out[(size_t)(row_base + i) * N_COLS + col] =
                        acc[tm][tn][i] * OIM_SCALAR;
            }
        }
    }
}

extern "C" void kernel_launch(void* const* d_in, const int* in_sizes, int n_in,
                              void* d_out, int out_size, void* d_ws, size_t ws_size,
                              hipStream_t stream) {
    // setup_inputs() order:
    // 0: inputs [2048,256], 1: non_id_feat [256,256], 2: lut [5532,256],
    // 3: cq [5000,256], 4: first_pos_sample, 5: second_pos_sample,
    // 6: targets (int), 7: belong_to_first_half, 8: header
    const float* inputs = (const float*)d_in[0];
    const float* nonid  = (const float*)d_in[1];
    const float* lut    = (const float*)d_in[2];
    const float* cq     = (const float*)d_in[3];
    float* out = (float*)d_out;

    const size_t ws_need = WS_A_BYTES + WS_B_BYTES;   // ~6.32 MiB
    if (d_ws != nullptr && ws_size >= ws_need) {
        bf16_t* Aperm = (bf16_t*)d_ws;
        bf16_t* Bperm = (bf16_t*)((char*)d_ws + WS_A_BYTES);
        oim_convert_kernel<<<dim3(CONV_BLOCKS), 256, 0, stream>>>(
            inputs, lut, cq, nonid, Aperm, Bperm);
        oim_gemm_dma<<<dim3(GRID_BLOCKS), 256, 0, stream>>>(Aperm, Bperm, out);
    } else {
        oim_gemm_kernel<<<dim3(GRID_BLOCKS), 256, 0, stream>>>(
            inputs, lut, cq, nonid, out);
    }
}